// Round 25
// baseline (32.190 us; speedup 1.0000x reference)
//
#include <hip/hip_runtime.h>

// AnatomicalConsistencyLoss: fused separable-Sobel magnitude + cosine loss.
// pred/target (2,1,160,160,160) f32 -> scalar f32.
// R25 = R22/R24 structure at HALF block granularity: 128-thread (2-wave)
// blocks, tile 32(x) x 8(y), DC=16 -> 2000 blocks. Total waves/CU unchanged
// (~15.6) but: barrier domain 4->2 waves (less straggle), 8 independent
// blocks/CU (2x independent streams for the CU scheduler), finer tail.
// Cost: staged halo ratio 1.41->1.56 (+10% fetch; HBM at 12%, irrelevant).
// Staging: wave w stages volume w, 2 GLD16 issues at dword bases 0 and 144
// (overlap 144..255 double-written with identical data - benign). 2-plane
// barrier interval (R22's proven best), 4 LDS plane-slots, 16.4KB.
// Pending-sum z-stream, packed-v2 math, fused transcendentals, XCD-chunked
// bijective swizzle (2000%8==0), two-kernel finalize, unroll pinned.

constexpr int Dd = 160, Hh = 160, Ww = 160;
constexpr int TW = 32, TH = 8, DC = 16;
constexpr int NTX = Ww / TW;                 // 5
constexpr int NTY = Hh / TH;                 // 20
constexpr int NTZ = Dd / DC;                 // 10
constexpr int NBLOCKS = NTX * NTY * NTZ * 2; // 2000
constexpr int NXCD = 8;
constexpr int CHUNK = NBLOCKS / NXCD;        // 250 (2000 % 8 == 0: bijective)
constexpr int PLANES = DC + 2;               // 18 = 9 intervals x 2 planes
constexpr int PLSZ = Hh * Ww;                // 25600
constexpr double NVOX = 2.0 * Dd * Hh * Ww;  // 8,192,000

constexpr int SPANF = 40;                    // floats staged per row (x0-4..x0+35)
constexpr int SROWS = TH + 2;                // 10 rows staged per plane
constexpr int VOLD  = SROWS * SPANF;         // 400 dwords of real data
constexpr int VOLF  = 512;                   // padded region per vol

typedef float v2 __attribute__((ext_vector_type(2)));
typedef float v4 __attribute__((ext_vector_type(4)));

#define GLD16(g, l)                                                     \
    __builtin_amdgcn_global_load_lds(                                   \
        (const __attribute__((address_space(1))) void*)(g),             \
        (__attribute__((address_space(3))) void*)(l), 16, 0, 0)

__global__ __launch_bounds__(128)
void acl_partial(const float* __restrict__ pred, const float* __restrict__ targ,
                 float2* __restrict__ partial)
{
    __shared__ float sv[4][2][VOLF];   // [plane-slot][vol][row*40+col], 16 KB
    __shared__ float rred[4];

    const int tid  = threadIdx.x;      // 0..127
    const int lane = tid & 63;
    const int w01  = tid >> 6;         // wave 0/1
    const int gx   = tid & 15;         // x-group of 2 output cols
    const int r    = tid >> 4;         // row 0..7

    // ---- XCD-chunked bijective swizzle + decode (zt fastest, wt, ht, b) ----
    const int bid = blockIdx.x;
    const int swz = (bid % NXCD) * CHUNK + bid / NXCD;
    const int zt  = swz % NTZ;
    const int t1  = swz / NTZ;
    const int wt  = t1 % NTX;
    const int t2  = t1 / NTX;
    const int ht  = t2 % NTY;
    const int b   = t2 / NTY;

    const int x0 = wt * TW, y0 = ht * TH;
    const int z0 = zt * DC;
    const size_t base = (size_t)b * ((size_t)Dd * PLSZ);
    const float* __restrict__ pv = pred + base;
    const float* __restrict__ tv = targ + base;

    // ---- staging constants: wave w01 stages volume w01, 2 issues ----
    // issue j covers dwords jbase + lane*4 of the 400-dword window
    int sp0, sp1;
    {
        auto mk = [&](int jbase) {
            int d = jbase + lane * 4;
            if (d > VOLD - 4) d = VOLD - 4;          // safety clamp (exact fit)
            const int row = d / SPANF;
            const int col = d - row * SPANF;         // multiple of 4
            int gy = y0 - 1 + row;  gy = gy < 0 ? 0 : (gy > Hh - 1 ? Hh - 1 : gy);
            int gxx = x0 - 4 + col; gxx = gxx < 0 ? 0 : (gxx > Ww - 4 ? Ww - 4 : gxx);
            return gy * Ww + gxx;
        };
        sp0 = mk(0); sp1 = mk(144);   // 144..399 overlaps 144..255: same data
    }
    const float* __restrict__ svol = (w01 == 0) ? pv : tv;

    // ---- consume constants ----
    const bool blkLo = (x0 == 0);
    const bool blkHi = (x0 + TW == Ww);
    const bool fixLo = blkLo && (gx == 0);
    const bool fixHi = blkHi && (gx == 15);
    const bool yokm  = (y0 + r - 1 >= 0);
    const bool yokp  = (y0 + r + 1 < Hh);
    const int  rb    = r * SPANF + 2 * gx + 3;   // col of X-1 in window row r

    const v2 z2 = {0.f, 0.f};
    const v4 z4 = {0.f, 0.f, 0.f, 0.f};

    // streaming pending partial gradients (named v2 scalars only)
    v2 P1x = z2, P1y = z2, P1z = z2, P2x = z2, P2y = z2, P2z = z2;
    v2 T1x = z2, T1y = z2, T1z = z2, T2x = z2, T2y = z2, T2z = z2;
    v2 accm = z2, accc = z2;

    auto stage = [&](int p1, int slot) {   // 2 GLD16 per wave, own volume
        int gz = z0 - 1 + p1;
        gz = gz < 0 ? 0 : (gz > Dd - 1 ? Dd - 1 : gz);
        const float* g = svol + (ptrdiff_t)gz * PLSZ;
        GLD16(g + sp0, &sv[slot][w01][0]);
        GLD16(g + sp1, &sv[slot][w01][144]);
    };

    // read 4-float span [X-1..X+2] of one staged row; zero invalid floats
    auto loadRow = [&](const float* S, int idx, bool valid) -> v4 {
        v4 row;
        row.x = fixLo ? 0.f : S[idx];
        row.y = S[idx + 1];
        row.z = S[idx + 2];
        row.w = fixHi ? 0.f : S[idx + 3];
        if (!valid) row = z4;
        return row;
    };

    auto consumeVol = [&](const float* S, v2& A, v2& B, v2& C) {
        const v4 m = loadRow(S, rb,             yokm);
        const v4 c = loadRow(S, rb + SPANF,     true);
        const v4 p = loadRow(S, rb + 2 * SPANF, yokp);
        const v2 HSm = m.xy + 2.f*m.yz + m.zw;
        const v2 HDm = m.zw - m.xy;
        const v2 HS0 = c.xy + 2.f*c.yz + c.zw;
        const v2 HD0 = c.zw - c.xy;
        const v2 HSp = p.xy + 2.f*p.yz + p.zw;
        const v2 HDp = p.zw - p.xy;
        A = HSm + 2.f*HS0 + HSp;   // sm_y(sm_x) -> z-deriv path
        B = HDm + 2.f*HD0 + HDp;   // sm_y(d_x)  -> x-gradient
        C = HSp - HSm;             // d_y(sm_x)  -> y-gradient
    };

    auto doPlane = [&](int p, int slot) {
        const bool zok = ((unsigned)(z0 - 1 + p) < (unsigned)Dd);   // wave-uniform

        v2 A, B, C;
        consumeVol(&sv[slot][0][0], A, B, C);
        if (!zok) { A = z2; B = z2; C = z2; }
        const v2 fpx = P1x + B, fpy = P1y + C, fpz = A - P1z;
        P1x = 2.f*B + P2x;  P1y = 2.f*C + P2y;  P1z = P2z;
        P2x = B;  P2y = C;  P2z = A;

        consumeVol(&sv[slot][1][0], A, B, C);
        if (!zok) { A = z2; B = z2; C = z2; }
        const v2 ftx = T1x + B, fty = T1y + C, ftz = A - T1z;
        T1x = 2.f*B + T2x;  T1y = 2.f*C + T2y;  T1z = T2z;
        T2x = B;  T2y = C;  T2z = A;

        if (p >= 2) {   // output plane z0 + (p-2) finalized
            // fused: (pm-tm)^2 = a+b-2*sqrt(ab);  rsq(np2)*rsq(nt2)=rsq(np2*nt2)
            const v2 np2 = fpx*fpx + fpy*fpy + fpz*fpz;
            const v2 nt2 = ftx*ftx + fty*fty + ftz*ftz;
            const v2 a  = np2 + 1e-8f;
            const v2 bb = nt2 + 1e-8f;
            const v2 ab = a * bb;
            v2 rt;
            rt.x = __builtin_amdgcn_sqrtf(ab.x);
            rt.y = __builtin_amdgcn_sqrtf(ab.y);
            accm += a + bb - 2.f*rt;
            const v2 dt = fpx*ftx + fpy*fty + fpz*ftz;
            v2 pr = np2 * nt2;
            pr.x = fmaxf(pr.x, 1e-30f);
            pr.y = fmaxf(pr.y, 1e-30f);
            v2 rq;
            rq.x = __builtin_amdgcn_rsqf(pr.x);
            rq.y = __builtin_amdgcn_rsqf(pr.y);
            accc += dt * rq;
        }
    };

    // ---- prologue: stage the first two planes ----
    stage(0, 0);
    stage(1, 1);
    __syncthreads();

    #pragma unroll 1   // CRITICAL: rolled (R16 lesson)
    for (int pp = 0; pp < PLANES; pp += 2) {
        if (pp + 2 < PLANES) stage(pp + 2, (pp + 2) & 3);
        if (pp + 3 < PLANES) stage(pp + 3, (pp + 3) & 3);

        doPlane(pp,     pp & 3);
        doPlane(pp + 1, (pp + 1) & 3);

        // one barrier per two planes: staged data landed (vmcnt drained) and
        // slots pp,pp+1 fully read before next interval's stage reuses them.
        __syncthreads();
    }

    // ---- block reduction (2 waves) ----
    float am = accm.x + accm.y;
    float ac = accc.x + accc.y;
    #pragma unroll
    for (int off = 32; off >= 1; off >>= 1) {
        am += __shfl_down(am, off);
        ac += __shfl_down(ac, off);
    }
    if (lane == 0) { rred[w01] = am; rred[2 + w01] = ac; }
    __syncthreads();
    if (tid == 0) {
        const float m = rred[0] + rred[1];
        const float c = rred[2] + rred[3];
        partial[bid] = make_float2(m, c);
    }
}

__global__ __launch_bounds__(256)
void acl_final(const float2* __restrict__ partial, float* __restrict__ out)
{
    __shared__ double sm[256], sc[256];
    double m = 0.0, c = 0.0;
    for (int i = threadIdx.x; i < NBLOCKS; i += 256) {
        const float2 v = partial[i];
        m += (double)v.x;
        c += (double)v.y;
    }
    sm[threadIdx.x] = m;
    sc[threadIdx.x] = c;
    __syncthreads();
    #pragma unroll
    for (int s = 128; s >= 1; s >>= 1) {
        if (threadIdx.x < (unsigned)s) {
            sm[threadIdx.x] += sm[threadIdx.x + s];
            sc[threadIdx.x] += sc[threadIdx.x + s];
        }
        __syncthreads();
    }
    if (threadIdx.x == 0) {
        const double mag_loss = sm[0] / NVOX;
        const double dir_loss = 1.0 - sc[0] / NVOX;
        out[0] = (float)(0.2 * (mag_loss + dir_loss));
    }
}

extern "C" void kernel_launch(void* const* d_in, const int* in_sizes, int n_in,
                              void* d_out, int out_size, void* d_ws, size_t ws_size,
                              hipStream_t stream) {
    const float* pred = (const float*)d_in[0];
    const float* targ = (const float*)d_in[1];
    float* out = (float*)d_out;
    float2* partial = (float2*)d_ws;  // 2000 * 8 B = 16 KB

    acl_partial<<<NBLOCKS, 128, 0, stream>>>(pred, targ, partial);
    acl_final<<<1, 256, 0, stream>>>(partial, out);
}

// Round 26
// 29.448 us; speedup vs baseline: 1.0931x; 1.0931x over previous
//
#include <hip/hip_runtime.h>

// AnatomicalConsistencyLoss: fused separable-Sobel magnitude + cosine loss.
// pred/target (2,1,160,160,160) f32 -> scalar f32.
// R26: COMBO-staged LDS. R24 plateau analysis: the longest per-wave chain is
// 24 scalar ds_read_b32/plane (3x-redundant horizontal combos). This round
// stages HORIZONTAL COMBOS instead of raw planes: 144 threads load their
// 4-col item's raw span global->reg (misaligned v4+v2, proven R10 pattern),
// compute HS/HD ONCE, write interleaved v4 {HS.xy,HD.xy} to LDS
// [slot][vol][18][17pad]. Consume = 3 aligned ds_read_b128 per vol (6 vs 24
// DS instrs) + ~25% less VALU. All y/x/z edge masking folded into the combo
// write (zero-fill) -> mask-free consume. Pipeline: issue loads p+2 at plane
// p (full-plane cover), combo+write p+1 after consume(p), 1 barrier/plane.
// Geometry/finalize: R24 (DC=16, 1000 blocks, XCD swizzle, two-kernel).
// Live state ~60 dwords (prefetch 12 + pending 24 + acc 4 + addr/temps):
// under the 64-VGPR wall. Unroll pinned (R16).

constexpr int Dd = 160, Hh = 160, Ww = 160;
constexpr int TW = 32, TH = 16, DC = 16;
constexpr int NTX = Ww / TW;                 // 5
constexpr int NTY = Hh / TH;                 // 10
constexpr int NTZ = Dd / DC;                 // 10
constexpr int NBLOCKS = NTX * NTY * NTZ * 2; // 1000
constexpr int NXCD = 8;
constexpr int CHUNK = NBLOCKS / NXCD;        // 125
constexpr int PLANES = DC + 2;               // 18
constexpr int PLSZ = Hh * Ww;                // 25600
constexpr double NVOX = 2.0 * Dd * Hh * Ww;  // 8,192,000

constexpr int CROWS = TH + 2;                // 18 combo rows
constexpr int CGP   = 17;                    // padded group stride (v4 units)
constexpr int NITEM = CROWS * 8;             // 144 combo items (4-col groups)

typedef float v2 __attribute__((ext_vector_type(2)));
typedef float v4 __attribute__((ext_vector_type(4)));
typedef float v4a __attribute__((ext_vector_type(4), aligned(4)));  // dword-aligned ok
typedef float v2a __attribute__((ext_vector_type(2), aligned(4)));

__global__ __launch_bounds__(256)
void acl_partial(const float* __restrict__ pred, const float* __restrict__ targ,
                 float2* __restrict__ partial)
{
    // {HS.xy, HD.xy} per 2-col group; b128-aligned; row stride 17 v4s (pad)
    __shared__ v4 cmb[2][2][CROWS][CGP];   // [slot][vol][row][grp], 19.1 KB
    __shared__ float rred[8];

    const int tid = threadIdx.x;
    const int gx  = tid & 15;        // consume: x-group of 2 output cols
    const int r   = tid >> 4;        // consume: row 0..15

    // ---- XCD-chunked bijective swizzle + decode (zt fastest, wt, ht, b) ----
    const int bid = blockIdx.x;
    const int swz = (bid % NXCD) * CHUNK + bid / NXCD;
    const int zt  = swz % NTZ;
    const int t1  = swz / NTZ;
    const int wt  = t1 % NTX;
    const int t2  = t1 / NTX;
    const int ht  = t2 % NTY;
    const int b   = t2 / NTY;

    const int x0 = wt * TW, y0 = ht * TH;
    const int z0 = zt * DC;
    const size_t base = (size_t)b * ((size_t)Dd * PLSZ);
    const float* __restrict__ pv = pred + base;
    const float* __restrict__ tv = targ + base;

    // ---- combo-item constants (tid < 144; others idle in combo phase) ----
    const bool hasItem = (tid < NITEM);
    const int crow = tid >> 3;                 // 0..17 (valid when hasItem)
    const int cg   = tid & 7;                  // 4-col group 0..7
    const int gyc  = y0 - 1 + crow;
    const bool yokc = hasItem && (gyc >= 0) && (gyc < Hh);
    int gycl = gyc < 0 ? 0 : (gyc > Hh - 1 ? Hh - 1 : gyc);
    const bool fixLo = (x0 == 0) && (cg == 0);
    const bool fixHi = (x0 + TW == Ww) && (cg == 7);
    const int xb = x0 + 4 * cg - 1;            // raw span e0 position
    const int a4 = gycl * Ww + (fixLo ? 0 : xb);          // v4 covers e0..e3 (or e1..e4)
    const int a2 = gycl * Ww + (fixHi ? (Ww - 2) : (xb + 4)); // v2 covers e4,e5 (or e3,e4)

    const v2 z2 = {0.f, 0.f};
    const v4 z4 = {0.f, 0.f, 0.f, 0.f};

    // streaming pending partial gradients (named v2 scalars only)
    v2 P1x = z2, P1y = z2, P1z = z2, P2x = z2, P2y = z2, P2z = z2;
    v2 T1x = z2, T1y = z2, T1z = z2, T2x = z2, T2y = z2, T2z = z2;
    v2 accm = z2, accc = z2;

    // prefetch registers (12 dwords)
    v4 pr4 = z4, tr4 = z4;
    v2 pr2 = z2, tr2 = z2;

    auto issueG = [&](int p2) {        // load raw spans for plane p2 into regs
        if (hasItem) {
            int gz = z0 - 1 + p2;
            gz = gz < 0 ? 0 : (gz > Dd - 1 ? Dd - 1 : gz);
            const float* pz = pv + (ptrdiff_t)gz * PLSZ;
            const float* tz = tv + (ptrdiff_t)gz * PLSZ;
            pr4 = *(const v4a*)(pz + a4);  pr2 = *(const v2a*)(pz + a2);
            tr4 = *(const v4a*)(tz + a4);  tr2 = *(const v2a*)(tz + a2);
        }
    };

    // assemble e0..e5 from the two loads, honoring edge fixups
    auto comboOne = [&](const v4 v, const v2 u, v4& w0, v4& w1) {
        float e0, e1, e2, e3, e4, e5;
        if (fixLo)      { e0 = 0.f;  e1 = v.x; e2 = v.y; e3 = v.z; e4 = v.w; e5 = u.y; }
        else if (fixHi) { e0 = v.x;  e1 = v.y; e2 = v.z; e3 = v.w; e4 = u.y; e5 = 0.f; }
        else            { e0 = v.x;  e1 = v.y; e2 = v.z; e3 = v.w; e4 = u.x; e5 = u.y; }
        const float HS0 = e0 + 2.f*e1 + e2, HS1 = e1 + 2.f*e2 + e3;
        const float HS2 = e2 + 2.f*e3 + e4, HS3 = e3 + 2.f*e4 + e5;
        w0 = (v4){HS0, HS1, e2 - e0, e3 - e1};
        w1 = (v4){HS2, HS3, e4 - e2, e5 - e3};
    };

    auto comboWrite = [&](int p1, int slot) {
        const bool zokc = ((unsigned)(z0 - 1 + p1) < (unsigned)Dd);
        const bool valid = zokc && yokc;
        v4 w0, w1;
        comboOne(pr4, pr2, w0, w1);
        if (!valid) { w0 = z4; w1 = z4; }
        if (hasItem) {
            cmb[slot][0][crow][2 * cg]     = w0;
            cmb[slot][0][crow][2 * cg + 1] = w1;
        }
        comboOne(tr4, tr2, w0, w1);
        if (!valid) { w0 = z4; w1 = z4; }
        if (hasItem) {
            cmb[slot][1][crow][2 * cg]     = w0;
            cmb[slot][1][crow][2 * cg + 1] = w1;
        }
    };

    auto consume = [&](int p, int s) {
        // pred
        {
            const v4 qm = cmb[s][0][r][gx], q0 = cmb[s][0][r + 1][gx], qp = cmb[s][0][r + 2][gx];
            const v2 A = qm.xy + 2.f*q0.xy + qp.xy;   // sm_y(HS) -> z path
            const v2 B = qm.zw + 2.f*q0.zw + qp.zw;   // sm_y(HD) -> x grad
            const v2 C = qp.xy - qm.xy;               // d_y(HS)  -> y grad
            const v2 fpx = P1x + B, fpy = P1y + C, fpz = A - P1z;
            P1x = 2.f*B + P2x;  P1y = 2.f*C + P2y;  P1z = P2z;
            P2x = B;  P2y = C;  P2z = A;
            // targ
            const v4 sm_ = cmb[s][1][r][gx], s0_ = cmb[s][1][r + 1][gx], sp_ = cmb[s][1][r + 2][gx];
            const v2 At = sm_.xy + 2.f*s0_.xy + sp_.xy;
            const v2 Bt = sm_.zw + 2.f*s0_.zw + sp_.zw;
            const v2 Ct = sp_.xy - sm_.xy;
            const v2 ftx = T1x + Bt, fty = T1y + Ct, ftz = At - T1z;
            T1x = 2.f*Bt + T2x;  T1y = 2.f*Ct + T2y;  T1z = T2z;
            T2x = Bt;  T2y = Ct;  T2z = At;

            if (p >= 2) {
                // fused: (pm-tm)^2 = a+b-2*sqrt(ab); rsq(n1)*rsq(n2)=rsq(n1*n2)
                const v2 np2 = fpx*fpx + fpy*fpy + fpz*fpz;
                const v2 nt2 = ftx*ftx + fty*fty + ftz*ftz;
                const v2 a  = np2 + 1e-8f;
                const v2 bb = nt2 + 1e-8f;
                const v2 ab = a * bb;
                v2 rt;
                rt.x = __builtin_amdgcn_sqrtf(ab.x);
                rt.y = __builtin_amdgcn_sqrtf(ab.y);
                accm += a + bb - 2.f*rt;
                const v2 dt = fpx*ftx + fpy*fty + fpz*ftz;
                v2 pr = np2 * nt2;
                pr.x = fmaxf(pr.x, 1e-30f);
                pr.y = fmaxf(pr.y, 1e-30f);
                v2 rq;
                rq.x = __builtin_amdgcn_rsqf(pr.x);
                rq.y = __builtin_amdgcn_rsqf(pr.y);
                accc += dt * rq;
            }
        }
    };

    // ---- prologue ----
    issueG(0);
    comboWrite(0, 0);     // compiler inserts the vmcnt wait on pr4/tr4 use
    issueG(1);
    __syncthreads();

    #pragma unroll 1
    for (int p = 0; p < PLANES; ++p) {
        const int s = p & 1;

        consume(p, s);                                // 6 b128 reads + math

        if (p + 1 < PLANES) comboWrite(p + 1, s ^ 1); // waits loads(p+1)
        if (p + 2 < PLANES) issueG(p + 2);            // full plane of cover

        __syncthreads();   // combo writes visible; orders slot reuse
    }

    // ---- block reduction ----
    float am = accm.x + accm.y;
    float ac = accc.x + accc.y;
    #pragma unroll
    for (int off = 32; off >= 1; off >>= 1) {
        am += __shfl_down(am, off);
        ac += __shfl_down(ac, off);
    }
    const int wid = tid >> 6;
    if ((tid & 63) == 0) { rred[wid] = am; rred[4 + wid] = ac; }
    __syncthreads();
    if (tid == 0) {
        const float m = rred[0] + rred[1] + rred[2] + rred[3];
        const float c = rred[4] + rred[5] + rred[6] + rred[7];
        partial[bid] = make_float2(m, c);
    }
}

__global__ __launch_bounds__(256)
void acl_final(const float2* __restrict__ partial, float* __restrict__ out)
{
    __shared__ double sm[256], sc[256];
    double m = 0.0, c = 0.0;
    for (int i = threadIdx.x; i < NBLOCKS; i += 256) {
        const float2 v = partial[i];
        m += (double)v.x;
        c += (double)v.y;
    }
    sm[threadIdx.x] = m;
    sc[threadIdx.x] = c;
    __syncthreads();
    #pragma unroll
    for (int s = 128; s >= 1; s >>= 1) {
        if (threadIdx.x < (unsigned)s) {
            sm[threadIdx.x] += sm[threadIdx.x + s];
            sc[threadIdx.x] += sc[threadIdx.x + s];
        }
        __syncthreads();
    }
    if (threadIdx.x == 0) {
        const double mag_loss = sm[0] / NVOX;
        const double dir_loss = 1.0 - sc[0] / NVOX;
        out[0] = (float)(0.2 * (mag_loss + dir_loss));
    }
}

extern "C" void kernel_launch(void* const* d_in, const int* in_sizes, int n_in,
                              void* d_out, int out_size, void* d_ws, size_t ws_size,
                              hipStream_t stream) {
    const float* pred = (const float*)d_in[0];
    const float* targ = (const float*)d_in[1];
    float* out = (float*)d_out;
    float2* partial = (float2*)d_ws;  // 1000 * 8 B = 8 KB

    acl_partial<<<NBLOCKS, 256, 0, stream>>>(pred, targ, partial);
    acl_final<<<1, 256, 0, stream>>>(partial, out);
}

// Round 27
// 28.908 us; speedup vs baseline: 1.1135x; 1.0187x over previous
//
#include <hip/hip_runtime.h>

// AnatomicalConsistencyLoss: fused separable-Sobel magnitude + cosine loss.
// pred/target (2,1,160,160,160) f32 -> scalar f32.
// R27 = R26 (combo-staged LDS, best 29.45us) + R22's barrier-interval lever:
// TWO planes per barrier (18 -> 9 barriers) using dual prefetch reg sets A/B
// (24 dwords). Interval: consume(pp),consume(pp+1) [ILP-interleaved chains]
// -> comboWrite(A->pp+2), comboWrite(B->pp+3) [loads issued ONE FULL
// INTERVAL ago -> ~2 planes of latency cover] -> issueG(A,pp+4),
// issueG(B,pp+5) -> one __syncthreads. Slots: consume {pp,pp+1}&3, write
// {pp+2,pp+3}&3 - disjoint; barrier orders reuse. Live state ~52 named
// dwords + temps (~70): spill gate = WRITE_SIZE < 1MB, else revert.
// Combo staging unchanged from R26: 144 item-threads load raw spans
// global->reg (misaligned v4+v2), compute HS/HD once, write interleaved
// {HS.xy,HD.xy} v4 pairs; consume = 3 aligned b128/vol, mask-free.
// Geometry/finalize: DC=16, 1000 blocks, XCD swizzle, two-kernel.

constexpr int Dd = 160, Hh = 160, Ww = 160;
constexpr int TW = 32, TH = 16, DC = 16;
constexpr int NTX = Ww / TW;                 // 5
constexpr int NTY = Hh / TH;                 // 10
constexpr int NTZ = Dd / DC;                 // 10
constexpr int NBLOCKS = NTX * NTY * NTZ * 2; // 1000
constexpr int NXCD = 8;
constexpr int CHUNK = NBLOCKS / NXCD;        // 125
constexpr int PLANES = DC + 2;               // 18 = 9 intervals x 2 planes
constexpr int PLSZ = Hh * Ww;                // 25600
constexpr double NVOX = 2.0 * Dd * Hh * Ww;  // 8,192,000

constexpr int CROWS = TH + 2;                // 18 combo rows
constexpr int CGP   = 17;                    // padded group stride (v4 units)
constexpr int NITEM = CROWS * 8;             // 144 combo items (4-col groups)

typedef float v2 __attribute__((ext_vector_type(2)));
typedef float v4 __attribute__((ext_vector_type(4)));
typedef float v4a __attribute__((ext_vector_type(4), aligned(4)));  // dword-aligned ok
typedef float v2a __attribute__((ext_vector_type(2), aligned(4)));

__global__ __launch_bounds__(256)
void acl_partial(const float* __restrict__ pred, const float* __restrict__ targ,
                 float2* __restrict__ partial)
{
    // {HS.xy, HD.xy} per 2-col group; b128-aligned; row stride 17 v4s (pad)
    __shared__ v4 cmb[4][2][CROWS][CGP];   // [slot][vol][row][grp], 38.25 KB
    __shared__ float rred[8];

    const int tid = threadIdx.x;
    const int gx  = tid & 15;        // consume: x-group of 2 output cols
    const int r   = tid >> 4;        // consume: row 0..15

    // ---- XCD-chunked bijective swizzle + decode (zt fastest, wt, ht, b) ----
    const int bid = blockIdx.x;
    const int swz = (bid % NXCD) * CHUNK + bid / NXCD;
    const int zt  = swz % NTZ;
    const int t1  = swz / NTZ;
    const int wt  = t1 % NTX;
    const int t2  = t1 / NTX;
    const int ht  = t2 % NTY;
    const int b   = t2 / NTY;

    const int x0 = wt * TW, y0 = ht * TH;
    const int z0 = zt * DC;
    const size_t base = (size_t)b * ((size_t)Dd * PLSZ);
    const float* __restrict__ pv = pred + base;
    const float* __restrict__ tv = targ + base;

    // ---- combo-item constants (tid < 144; others idle in combo phase) ----
    const bool hasItem = (tid < NITEM);
    const int crow = tid >> 3;                 // 0..17 (valid when hasItem)
    const int cg   = tid & 7;                  // 4-col group 0..7
    const int gyc  = y0 - 1 + crow;
    const bool yokc = hasItem && (gyc >= 0) && (gyc < Hh);
    int gycl = gyc < 0 ? 0 : (gyc > Hh - 1 ? Hh - 1 : gyc);
    const bool fixLo = (x0 == 0) && (cg == 0);
    const bool fixHi = (x0 + TW == Ww) && (cg == 7);
    const int xb = x0 + 4 * cg - 1;            // raw span e0 position
    const int a4 = gycl * Ww + (fixLo ? 0 : xb);              // v4: e0..e3 (or e1..e4)
    const int a2 = gycl * Ww + (fixHi ? (Ww - 2) : (xb + 4)); // v2: e4,e5 (or e3,e4)

    const v2 z2 = {0.f, 0.f};
    const v4 z4 = {0.f, 0.f, 0.f, 0.f};

    // streaming pending partial gradients (named v2 scalars only)
    v2 P1x = z2, P1y = z2, P1z = z2, P2x = z2, P2y = z2, P2z = z2;
    v2 T1x = z2, T1y = z2, T1z = z2, T2x = z2, T2y = z2, T2z = z2;
    v2 accm = z2, accc = z2;

    // dual prefetch reg sets A/B (12 dwords each)
    v4 pA4 = z4, tA4 = z4, pB4 = z4, tB4 = z4;
    v2 pA2 = z2, tA2 = z2, pB2 = z2, tB2 = z2;

    auto issueG = [&](v4& q4, v2& q2, v4& s4, v2& s2, int p2) {
        if (hasItem) {
            int gz = z0 - 1 + p2;
            gz = gz < 0 ? 0 : (gz > Dd - 1 ? Dd - 1 : gz);
            const float* pz = pv + (ptrdiff_t)gz * PLSZ;
            const float* tz = tv + (ptrdiff_t)gz * PLSZ;
            q4 = *(const v4a*)(pz + a4);  q2 = *(const v2a*)(pz + a2);
            s4 = *(const v4a*)(tz + a4);  s2 = *(const v2a*)(tz + a2);
        }
    };

    // assemble e0..e5 from the two loads, honoring edge fixups
    auto comboOne = [&](const v4 v, const v2 u, v4& w0, v4& w1) {
        float e0, e1, e2, e3, e4, e5;
        if (fixLo)      { e0 = 0.f;  e1 = v.x; e2 = v.y; e3 = v.z; e4 = v.w; e5 = u.y; }
        else if (fixHi) { e0 = v.x;  e1 = v.y; e2 = v.z; e3 = v.w; e4 = u.y; e5 = 0.f; }
        else            { e0 = v.x;  e1 = v.y; e2 = v.z; e3 = v.w; e4 = u.x; e5 = u.y; }
        const float HS0 = e0 + 2.f*e1 + e2, HS1 = e1 + 2.f*e2 + e3;
        const float HS2 = e2 + 2.f*e3 + e4, HS3 = e3 + 2.f*e4 + e5;
        w0 = (v4){HS0, HS1, e2 - e0, e3 - e1};
        w1 = (v4){HS2, HS3, e4 - e2, e5 - e3};
    };

    auto comboWrite = [&](const v4 q4, const v2 q2, const v4 s4, const v2 s2,
                          int p1, int slot) {
        const bool zokc = ((unsigned)(z0 - 1 + p1) < (unsigned)Dd);
        const bool valid = zokc && yokc;
        v4 w0, w1;
        comboOne(q4, q2, w0, w1);
        if (!valid) { w0 = z4; w1 = z4; }
        if (hasItem) {
            cmb[slot][0][crow][2 * cg]     = w0;
            cmb[slot][0][crow][2 * cg + 1] = w1;
        }
        comboOne(s4, s2, w0, w1);
        if (!valid) { w0 = z4; w1 = z4; }
        if (hasItem) {
            cmb[slot][1][crow][2 * cg]     = w0;
            cmb[slot][1][crow][2 * cg + 1] = w1;
        }
    };

    auto consume = [&](int p, int s) {
        const v4 qm = cmb[s][0][r][gx], q0 = cmb[s][0][r + 1][gx], qp = cmb[s][0][r + 2][gx];
        const v2 A = qm.xy + 2.f*q0.xy + qp.xy;   // sm_y(HS) -> z path
        const v2 B = qm.zw + 2.f*q0.zw + qp.zw;   // sm_y(HD) -> x grad
        const v2 C = qp.xy - qm.xy;               // d_y(HS)  -> y grad
        const v2 fpx = P1x + B, fpy = P1y + C, fpz = A - P1z;
        P1x = 2.f*B + P2x;  P1y = 2.f*C + P2y;  P1z = P2z;
        P2x = B;  P2y = C;  P2z = A;

        const v4 sm_ = cmb[s][1][r][gx], s0_ = cmb[s][1][r + 1][gx], sp_ = cmb[s][1][r + 2][gx];
        const v2 At = sm_.xy + 2.f*s0_.xy + sp_.xy;
        const v2 Bt = sm_.zw + 2.f*s0_.zw + sp_.zw;
        const v2 Ct = sp_.xy - sm_.xy;
        const v2 ftx = T1x + Bt, fty = T1y + Ct, ftz = At - T1z;
        T1x = 2.f*Bt + T2x;  T1y = 2.f*Ct + T2y;  T1z = T2z;
        T2x = Bt;  T2y = Ct;  T2z = At;

        if (p >= 2) {
            // fused: (pm-tm)^2 = a+b-2*sqrt(ab); rsq(n1)*rsq(n2)=rsq(n1*n2)
            const v2 np2 = fpx*fpx + fpy*fpy + fpz*fpz;
            const v2 nt2 = ftx*ftx + fty*fty + ftz*ftz;
            const v2 a  = np2 + 1e-8f;
            const v2 bb = nt2 + 1e-8f;
            const v2 ab = a * bb;
            v2 rt;
            rt.x = __builtin_amdgcn_sqrtf(ab.x);
            rt.y = __builtin_amdgcn_sqrtf(ab.y);
            accm += a + bb - 2.f*rt;
            const v2 dt = fpx*ftx + fpy*fty + fpz*ftz;
            v2 pr = np2 * nt2;
            pr.x = fmaxf(pr.x, 1e-30f);
            pr.y = fmaxf(pr.y, 1e-30f);
            v2 rq;
            rq.x = __builtin_amdgcn_rsqf(pr.x);
            rq.y = __builtin_amdgcn_rsqf(pr.y);
            accc += dt * rq;
        }
    };

    // ---- prologue: combo-write planes 0,1; issue loads for planes 2,3 ----
    issueG(pA4, pA2, tA4, tA2, 0);
    issueG(pB4, pB2, tB4, tB2, 1);
    comboWrite(pA4, pA2, tA4, tA2, 0, 0);   // vmcnt wait inserted by compiler
    comboWrite(pB4, pB2, tB4, tB2, 1, 1);
    issueG(pA4, pA2, tA4, tA2, 2);
    issueG(pB4, pB2, tB4, tB2, 3);
    __syncthreads();

    #pragma unroll 1   // CRITICAL: rolled (R16 lesson)
    for (int pp = 0; pp < PLANES; pp += 2) {
        consume(pp,     pp & 3);
        consume(pp + 1, (pp + 1) & 3);

        // combo-write planes pp+2,pp+3 (their loads have 1 interval of cover),
        // then issue loads for pp+4,pp+5. Slots disjoint from consumed ones.
        if (pp + 2 < PLANES) comboWrite(pA4, pA2, tA4, tA2, pp + 2, (pp + 2) & 3);
        if (pp + 3 < PLANES) comboWrite(pB4, pB2, tB4, tB2, pp + 3, (pp + 3) & 3);
        if (pp + 4 < PLANES) issueG(pA4, pA2, tA4, tA2, pp + 4);
        if (pp + 5 < PLANES) issueG(pB4, pB2, tB4, tB2, pp + 5);

        __syncthreads();   // writes visible; orders slot reuse next interval
    }

    // ---- block reduction ----
    float am = accm.x + accm.y;
    float ac = accc.x + accc.y;
    #pragma unroll
    for (int off = 32; off >= 1; off >>= 1) {
        am += __shfl_down(am, off);
        ac += __shfl_down(ac, off);
    }
    const int wid = tid >> 6;
    if ((tid & 63) == 0) { rred[wid] = am; rred[4 + wid] = ac; }
    __syncthreads();
    if (tid == 0) {
        const float m = rred[0] + rred[1] + rred[2] + rred[3];
        const float c = rred[4] + rred[5] + rred[6] + rred[7];
        partial[bid] = make_float2(m, c);
    }
}

__global__ __launch_bounds__(256)
void acl_final(const float2* __restrict__ partial, float* __restrict__ out)
{
    __shared__ double sm[256], sc[256];
    double m = 0.0, c = 0.0;
    for (int i = threadIdx.x; i < NBLOCKS; i += 256) {
        const float2 v = partial[i];
        m += (double)v.x;
        c += (double)v.y;
    }
    sm[threadIdx.x] = m;
    sc[threadIdx.x] = c;
    __syncthreads();
    #pragma unroll
    for (int s = 128; s >= 1; s >>= 1) {
        if (threadIdx.x < (unsigned)s) {
            sm[threadIdx.x] += sm[threadIdx.x + s];
            sc[threadIdx.x] += sc[threadIdx.x + s];
        }
        __syncthreads();
    }
    if (threadIdx.x == 0) {
        const double mag_loss = sm[0] / NVOX;
        const double dir_loss = 1.0 - sc[0] / NVOX;
        out[0] = (float)(0.2 * (mag_loss + dir_loss));
    }
}

extern "C" void kernel_launch(void* const* d_in, const int* in_sizes, int n_in,
                              void* d_out, int out_size, void* d_ws, size_t ws_size,
                              hipStream_t stream) {
    const float* pred = (const float*)d_in[0];
    const float* targ = (const float*)d_in[1];
    float* out = (float*)d_out;
    float2* partial = (float2*)d_ws;  // 1000 * 8 B = 8 KB

    acl_partial<<<NBLOCKS, 256, 0, stream>>>(pred, targ, partial);
    acl_final<<<1, 256, 0, stream>>>(partial, out);
}

// Round 28
// 28.413 us; speedup vs baseline: 1.1330x; 1.0174x over previous
//
#include <hip/hip_runtime.h>

// AnatomicalConsistencyLoss: fused separable-Sobel magnitude + cosine loss.
// pred/target (2,1,160,160,160) f32 -> scalar f32.
// R28 = R27 (combo-staged LDS + 2-plane barrier interval, best 28.91us) with
// the combo phase LOAD-BALANCED: items split per volume -> 288 vol-items
// (18 rows x 8 grps x 2 vols). All 256 threads take one item (R27: 144
// threads took 2-volume items, 112 idle); threads 0-31 take a second.
// Most threads now run ONE comboOne per plane instead of two -> combo-phase
// VALU per thread ~halves, idle threads gone. PF reg cost unchanged (each
// set 12 dwords = primary 6 + secondary 6). Dual-set 2-plane interval, slot
// algebra, mask-free consume, DC=16/1000 blocks, XCD swizzle, two-kernel
// finalize: byte-identical to R27. Spill gate: WRITE_SIZE < 1MB else revert.

constexpr int Dd = 160, Hh = 160, Ww = 160;
constexpr int TW = 32, TH = 16, DC = 16;
constexpr int NTX = Ww / TW;                 // 5
constexpr int NTY = Hh / TH;                 // 10
constexpr int NTZ = Dd / DC;                 // 10
constexpr int NBLOCKS = NTX * NTY * NTZ * 2; // 1000
constexpr int NXCD = 8;
constexpr int CHUNK = NBLOCKS / NXCD;        // 125
constexpr int PLANES = DC + 2;               // 18 = 9 intervals x 2 planes
constexpr int PLSZ = Hh * Ww;                // 25600
constexpr double NVOX = 2.0 * Dd * Hh * Ww;  // 8,192,000

constexpr int CROWS = TH + 2;                // 18 combo rows
constexpr int CGP   = 17;                    // padded group stride (v4 units)
constexpr int SLOTV4 = 2 * CROWS * CGP;      // v4s per slot (612)

typedef float v2 __attribute__((ext_vector_type(2)));
typedef float v4 __attribute__((ext_vector_type(4)));
typedef float v4a __attribute__((ext_vector_type(4), aligned(4)));  // dword-aligned ok
typedef float v2a __attribute__((ext_vector_type(2), aligned(4)));

__global__ __launch_bounds__(256)
void acl_partial(const float* __restrict__ pred, const float* __restrict__ targ,
                 float2* __restrict__ partial)
{
    // {HS.xy, HD.xy} per 2-col group; b128-aligned; row stride 17 v4s (pad)
    __shared__ v4 cmb[4][2][CROWS][CGP];   // [slot][vol][row][grp], 39.2 KB
    __shared__ float rred[8];

    const int tid = threadIdx.x;
    const int gx  = tid & 15;        // consume: x-group of 2 output cols
    const int r   = tid >> 4;        // consume: row 0..15

    // ---- XCD-chunked bijective swizzle + decode (zt fastest, wt, ht, b) ----
    const int bid = blockIdx.x;
    const int swz = (bid % NXCD) * CHUNK + bid / NXCD;
    const int zt  = swz % NTZ;
    const int t1  = swz / NTZ;
    const int wt  = t1 % NTX;
    const int t2  = t1 / NTX;
    const int ht  = t2 % NTY;
    const int b   = t2 / NTY;

    const int x0 = wt * TW, y0 = ht * TH;
    const int z0 = zt * DC;
    const size_t base = (size_t)b * ((size_t)Dd * PLSZ);
    const float* __restrict__ pv = pred + base;
    const float* __restrict__ tv = targ + base;

    // ---- per-volume combo items: vitem v in [0,288): row=v>>4, sub=v&15,
    //      vol=sub&1, cg=sub>>1. Primary = tid; secondary (tid<32) = 256+tid.
    const bool hasSec = (tid < 32);

    struct ItemC { int a4, a2, bo; bool fixLo, fixHi, yok, isT; };
    auto mkItem = [&](int v, ItemC& it) {
        const int row = v >> 4;
        const int sub = v & 15;
        const int vol = sub & 1;
        const int cg  = sub >> 1;
        const int gy  = y0 - 1 + row;
        it.yok = (gy >= 0) && (gy < Hh);
        const int gycl = gy < 0 ? 0 : (gy > Hh - 1 ? Hh - 1 : gy);
        it.fixLo = (x0 == 0) && (cg == 0);
        it.fixHi = (x0 + TW == Ww) && (cg == 7);
        const int xb = x0 + 4 * cg - 1;
        it.a4 = gycl * Ww + (it.fixLo ? 0 : xb);              // v4: e0..e3 (or e1..e4)
        it.a2 = gycl * Ww + (it.fixHi ? (Ww - 2) : (xb + 4)); // v2: e4,e5 (or e3,e4)
        it.bo = (vol * CROWS + row) * CGP + 2 * cg;           // v4 offset in slot
        it.isT = (vol != 0);
    };
    ItemC itP, itS;
    mkItem(tid, itP);
    mkItem(hasSec ? 256 + tid : tid, itS);   // dummy for non-sec (never used)

    const v2 z2 = {0.f, 0.f};
    const v4 z4 = {0.f, 0.f, 0.f, 0.f};

    // streaming pending partial gradients (named v2 scalars only)
    v2 P1x = z2, P1y = z2, P1z = z2, P2x = z2, P2y = z2, P2z = z2;
    v2 T1x = z2, T1y = z2, T1z = z2, T2x = z2, T2y = z2, T2z = z2;
    v2 accm = z2, accc = z2;

    // dual prefetch reg sets A/B (12 dwords each: primary v4+v2, secondary v4+v2)
    v4 pA4 = z4, sA4 = z4, pB4 = z4, sB4 = z4;
    v2 pA2 = z2, sA2 = z2, pB2 = z2, sB2 = z2;

    auto issueG = [&](v4& q4, v2& q2, v4& s4, v2& s2, int p2) {
        int gz = z0 - 1 + p2;
        gz = gz < 0 ? 0 : (gz > Dd - 1 ? Dd - 1 : gz);
        const float* zp = (itP.isT ? tv : pv) + (ptrdiff_t)gz * PLSZ;
        q4 = *(const v4a*)(zp + itP.a4);
        q2 = *(const v2a*)(zp + itP.a2);
        if (hasSec) {
            const float* zs = (itS.isT ? tv : pv) + (ptrdiff_t)gz * PLSZ;
            s4 = *(const v4a*)(zs + itS.a4);
            s2 = *(const v2a*)(zs + itS.a2);
        }
    };

    // assemble e0..e5 from the two loads, honoring edge fixups
    auto comboOne = [&](const ItemC& it, const v4 v, const v2 u, v4& w0, v4& w1) {
        float e0, e1, e2, e3, e4, e5;
        if (it.fixLo)      { e0 = 0.f;  e1 = v.x; e2 = v.y; e3 = v.z; e4 = v.w; e5 = u.y; }
        else if (it.fixHi) { e0 = v.x;  e1 = v.y; e2 = v.z; e3 = v.w; e4 = u.y; e5 = 0.f; }
        else               { e0 = v.x;  e1 = v.y; e2 = v.z; e3 = v.w; e4 = u.x; e5 = u.y; }
        const float HS0 = e0 + 2.f*e1 + e2, HS1 = e1 + 2.f*e2 + e3;
        const float HS2 = e2 + 2.f*e3 + e4, HS3 = e3 + 2.f*e4 + e5;
        w0 = (v4){HS0, HS1, e2 - e0, e3 - e1};
        w1 = (v4){HS2, HS3, e4 - e2, e5 - e3};
    };

    auto comboWrite = [&](const v4 q4, const v2 q2, const v4 s4, const v2 s2,
                          int p1, int slot) {
        const bool zokc = ((unsigned)(z0 - 1 + p1) < (unsigned)Dd);
        v4* sb = &cmb[slot][0][0][0];
        v4 w0, w1;
        comboOne(itP, q4, q2, w0, w1);
        if (!(zokc && itP.yok)) { w0 = z4; w1 = z4; }
        sb[itP.bo]     = w0;
        sb[itP.bo + 1] = w1;
        if (hasSec) {
            comboOne(itS, s4, s2, w0, w1);
            if (!(zokc && itS.yok)) { w0 = z4; w1 = z4; }
            sb[itS.bo]     = w0;
            sb[itS.bo + 1] = w1;
        }
    };

    auto consume = [&](int p, int s) {
        const v4 qm = cmb[s][0][r][gx], q0 = cmb[s][0][r + 1][gx], qp = cmb[s][0][r + 2][gx];
        const v2 A = qm.xy + 2.f*q0.xy + qp.xy;   // sm_y(HS) -> z path
        const v2 B = qm.zw + 2.f*q0.zw + qp.zw;   // sm_y(HD) -> x grad
        const v2 C = qp.xy - qm.xy;               // d_y(HS)  -> y grad
        const v2 fpx = P1x + B, fpy = P1y + C, fpz = A - P1z;
        P1x = 2.f*B + P2x;  P1y = 2.f*C + P2y;  P1z = P2z;
        P2x = B;  P2y = C;  P2z = A;

        const v4 sm_ = cmb[s][1][r][gx], s0_ = cmb[s][1][r + 1][gx], sp_ = cmb[s][1][r + 2][gx];
        const v2 At = sm_.xy + 2.f*s0_.xy + sp_.xy;
        const v2 Bt = sm_.zw + 2.f*s0_.zw + sp_.zw;
        const v2 Ct = sp_.xy - sm_.xy;
        const v2 ftx = T1x + Bt, fty = T1y + Ct, ftz = At - T1z;
        T1x = 2.f*Bt + T2x;  T1y = 2.f*Ct + T2y;  T1z = T2z;
        T2x = Bt;  T2y = Ct;  T2z = At;

        if (p >= 2) {
            // fused: (pm-tm)^2 = a+b-2*sqrt(ab); rsq(n1)*rsq(n2)=rsq(n1*n2)
            const v2 np2 = fpx*fpx + fpy*fpy + fpz*fpz;
            const v2 nt2 = ftx*ftx + fty*fty + ftz*ftz;
            const v2 a  = np2 + 1e-8f;
            const v2 bb = nt2 + 1e-8f;
            const v2 ab = a * bb;
            v2 rt;
            rt.x = __builtin_amdgcn_sqrtf(ab.x);
            rt.y = __builtin_amdgcn_sqrtf(ab.y);
            accm += a + bb - 2.f*rt;
            const v2 dt = fpx*ftx + fpy*fty + fpz*ftz;
            v2 pr = np2 * nt2;
            pr.x = fmaxf(pr.x, 1e-30f);
            pr.y = fmaxf(pr.y, 1e-30f);
            v2 rq;
            rq.x = __builtin_amdgcn_rsqf(pr.x);
            rq.y = __builtin_amdgcn_rsqf(pr.y);
            accc += dt * rq;
        }
    };

    // ---- prologue: combo-write planes 0,1; issue loads for planes 2,3 ----
    issueG(pA4, pA2, sA4, sA2, 0);
    issueG(pB4, pB2, sB4, sB2, 1);
    comboWrite(pA4, pA2, sA4, sA2, 0, 0);   // vmcnt wait inserted by compiler
    comboWrite(pB4, pB2, sB4, sB2, 1, 1);
    issueG(pA4, pA2, sA4, sA2, 2);
    issueG(pB4, pB2, sB4, sB2, 3);
    __syncthreads();

    #pragma unroll 1   // CRITICAL: rolled (R16 lesson)
    for (int pp = 0; pp < PLANES; pp += 2) {
        consume(pp,     pp & 3);
        consume(pp + 1, (pp + 1) & 3);

        // combo-write planes pp+2,pp+3 (loads have 1 interval of cover),
        // then issue loads for pp+4,pp+5. Slots disjoint from consumed ones.
        if (pp + 2 < PLANES) comboWrite(pA4, pA2, sA4, sA2, pp + 2, (pp + 2) & 3);
        if (pp + 3 < PLANES) comboWrite(pB4, pB2, sB4, sB2, pp + 3, (pp + 3) & 3);
        if (pp + 4 < PLANES) issueG(pA4, pA2, sA4, sA2, pp + 4);
        if (pp + 5 < PLANES) issueG(pB4, pB2, sB4, sB2, pp + 5);

        __syncthreads();   // writes visible; orders slot reuse next interval
    }

    // ---- block reduction ----
    float am = accm.x + accm.y;
    float ac = accc.x + accc.y;
    #pragma unroll
    for (int off = 32; off >= 1; off >>= 1) {
        am += __shfl_down(am, off);
        ac += __shfl_down(ac, off);
    }
    const int wid = tid >> 6;
    if ((tid & 63) == 0) { rred[wid] = am; rred[4 + wid] = ac; }
    __syncthreads();
    if (tid == 0) {
        const float m = rred[0] + rred[1] + rred[2] + rred[3];
        const float c = rred[4] + rred[5] + rred[6] + rred[7];
        partial[bid] = make_float2(m, c);
    }
}

__global__ __launch_bounds__(256)
void acl_final(const float2* __restrict__ partial, float* __restrict__ out)
{
    __shared__ double sm[256], sc[256];
    double m = 0.0, c = 0.0;
    for (int i = threadIdx.x; i < NBLOCKS; i += 256) {
        const float2 v = partial[i];
        m += (double)v.x;
        c += (double)v.y;
    }
    sm[threadIdx.x] = m;
    sc[threadIdx.x] = c;
    __syncthreads();
    #pragma unroll
    for (int s = 128; s >= 1; s >>= 1) {
        if (threadIdx.x < (unsigned)s) {
            sm[threadIdx.x] += sm[threadIdx.x + s];
            sc[threadIdx.x] += sc[threadIdx.x + s];
        }
        __syncthreads();
    }
    if (threadIdx.x == 0) {
        const double mag_loss = sm[0] / NVOX;
        const double dir_loss = 1.0 - sc[0] / NVOX;
        out[0] = (float)(0.2 * (mag_loss + dir_loss));
    }
}

extern "C" void kernel_launch(void* const* d_in, const int* in_sizes, int n_in,
                              void* d_out, int out_size, void* d_ws, size_t ws_size,
                              hipStream_t stream) {
    const float* pred = (const float*)d_in[0];
    const float* targ = (const float*)d_in[1];
    float* out = (float*)d_out;
    float2* partial = (float2*)d_ws;  // 1000 * 8 B = 8 KB

    acl_partial<<<NBLOCKS, 256, 0, stream>>>(pred, targ, partial);
    acl_final<<<1, 256, 0, stream>>>(partial, out);
}